// Round 1
// baseline (1527.840 us; speedup 1.0000x reference)
//
#include <hip/hip_runtime.h>
#include <math.h>

#define B_ 128
#define L_ 1024
#define E_ 1280
#define H_ 128
#define DA_ 512
#define DB_ 768
#define FEAT_ 1280
#define EPS_ 1e-5f
#define NS_ 16
#define CHUNK_ (L_ / NS_)   // 64 rows per slice

// ---------------- ragged mean pool ----------------
// grid (B, NS_), block 320 (E/4 float4 lanes). Each block sums rows
// [s*CHUNK, min((s+1)*CHUNK, len)) and atomically adds (sum/len) partials.
__global__ void pool_kernel(const float* __restrict__ esm,
                            const int* __restrict__ vlens,
                            float* __restrict__ pool) {
    const int b = blockIdx.x;
    const int s = blockIdx.y;
    const int len = vlens[b] + 2;
    int l0 = s * CHUNK_;
    int l1 = min(l0 + CHUNK_, len);
    if (l0 >= l1) return;
    const int e4 = threadIdx.x;  // 0..319
    const float4* base = (const float4*)esm + (size_t)b * L_ * (E_ / 4) + e4;
    float sx = 0.f, sy = 0.f, sz = 0.f, sw = 0.f;
    #pragma unroll 4
    for (int l = l0; l < l1; ++l) {
        float4 v = base[(size_t)l * (E_ / 4)];
        sx += v.x; sy += v.y; sz += v.z; sw += v.w;
    }
    const float inv = 1.0f / (float)len;
    float* dst = pool + (size_t)b * E_ + e4 * 4;
    atomicAdd(dst + 0, sx * inv);
    atomicAdd(dst + 1, sy * inv);
    atomicAdd(dst + 2, sz * inv);
    atomicAdd(dst + 3, sw * inv);
}

// ---------------- per-column standardize (over batch, ddof=1) ----------------
// grid FEAT_ (one block per output column), block B_ (=128, one thread per row).
// Reference standardizes a/b separately then re-standardizes the concat; the
// second pass is identity on already-standardized columns, so one pass.
__global__ void standardize_kernel(const float* __restrict__ ma,
                                   const float* __restrict__ mb,
                                   float* __restrict__ cross) {
    const int c = blockIdx.x;   // 0..1279
    const int t = threadIdx.x;  // 0..127
    const float* src; int d, col;
    if (c < DA_) { src = ma; d = DA_; col = c; }
    else         { src = mb; d = DB_; col = c - DA_; }
    const float v = src[(size_t)t * d + col];
    __shared__ float red[B_];
    red[t] = v; __syncthreads();
    for (int off = B_ / 2; off > 0; off >>= 1) {
        if (t < off) red[t] += red[t + off];
        __syncthreads();
    }
    const float mean = red[0] * (1.0f / B_);
    __syncthreads();
    const float dv = v - mean;
    red[t] = dv * dv; __syncthreads();
    for (int off = B_ / 2; off > 0; off >>= 1) {
        if (t < off) red[t] += red[t + off];
        __syncthreads();
    }
    const float stdv = sqrtf(red[0] * (1.0f / (B_ - 1)));
    cross[(size_t)t * FEAT_ + c] = dv / stdv;
}

// ---------------- fp32 tiled GEMM: C = act(A[M,K] @ W[K,N] + bias) ----------------
// BM=BN=64, BK=16, 256 threads, 4x4 micro-tile per thread.
// LDS leading dim 68: keeps float4 (16B) alignment, 2-way bank aliasing only (free).
__global__ __launch_bounds__(256) void gemm_kernel(
    const float* __restrict__ A, const float* __restrict__ W,
    const float* __restrict__ bias, float* __restrict__ C,
    const int M, const int N, const int K, const int relu) {
    __shared__ float As[16][68];  // [k][m]
    __shared__ float Ws[16][68];  // [k][n]
    const int bm = blockIdx.x * 64;
    const int bn = blockIdx.y * 64;
    const int tid = threadIdx.x;
    const int tx = tid & 15;   // col group
    const int ty = tid >> 4;   // row group
    const int akk = tid & 15;  // A-load k
    const int ar  = tid >> 4;  // A-load row base
    const int wn  = tid & 63;  // W-load col
    const int wk  = tid >> 6;  // W-load k base
    float acc[4][4] = {};
    for (int k0 = 0; k0 < K; k0 += 16) {
        #pragma unroll
        for (int i = 0; i < 4; ++i) {
            As[akk][ar + i * 16] = A[(size_t)(bm + ar + i * 16) * K + k0 + akk];
            Ws[wk + i * 4][wn]   = W[(size_t)(k0 + wk + i * 4) * N + bn + wn];
        }
        __syncthreads();
        #pragma unroll
        for (int kk = 0; kk < 16; ++kk) {
            float4 a4 = *(const float4*)&As[kk][ty * 4];
            float4 w4 = *(const float4*)&Ws[kk][tx * 4];
            const float av[4] = {a4.x, a4.y, a4.z, a4.w};
            const float wv[4] = {w4.x, w4.y, w4.z, w4.w};
            #pragma unroll
            for (int i = 0; i < 4; ++i)
                #pragma unroll
                for (int j = 0; j < 4; ++j)
                    acc[i][j] += av[i] * wv[j];
        }
        __syncthreads();
    }
    #pragma unroll
    for (int i = 0; i < 4; ++i) {
        const int row = bm + ty * 4 + i;
        float4 o;
        float* op = (float*)&o;
        #pragma unroll
        for (int j = 0; j < 4; ++j) {
            float v = acc[i][j];
            if (bias) v += bias[bn + tx * 4 + j];
            if (relu) v = fmaxf(v, 0.0f);
            op[j] = v;
        }
        *(float4*)&C[(size_t)row * N + bn + tx * 4] = o;
    }
}

// ---------------- layernorm over last dim (H=128), ddof=0 ----------------
__global__ void ln_kernel(const float* __restrict__ x, const float* __restrict__ g,
                          const float* __restrict__ bt, float* __restrict__ out) {
    const int r = blockIdx.x;
    const int t = threadIdx.x;  // 0..127
    const float v = x[(size_t)r * H_ + t];
    __shared__ float red[H_];
    red[t] = v; __syncthreads();
    for (int off = H_ / 2; off > 0; off >>= 1) {
        if (t < off) red[t] += red[t + off];
        __syncthreads();
    }
    const float mean = red[0] * (1.0f / H_);
    __syncthreads();
    const float dv = v - mean;
    red[t] = dv * dv; __syncthreads();
    for (int off = H_ / 2; off > 0; off >>= 1) {
        if (t < off) red[t] += red[t + off];
        __syncthreads();
    }
    const float var = red[0] * (1.0f / H_);
    out[(size_t)r * H_ + t] = dv * rsqrtf(var + EPS_) * g[t] + bt[t];
}

extern "C" void kernel_launch(void* const* d_in, const int* in_sizes, int n_in,
                              void* d_out, int out_size, void* d_ws, size_t ws_size,
                              hipStream_t stream) {
    const float* esm  = (const float*)d_in[0];
    const int*   vlen = (const int*)d_in[1];
    const float* ma   = (const float*)d_in[2];
    const float* mb   = (const float*)d_in[3];
    const float* lw1  = (const float*)d_in[4];
    const float* lb1  = (const float*)d_in[5];
    const float* lw2  = (const float*)d_in[6];
    const float* lb2  = (const float*)d_in[7];
    const float* mw1  = (const float*)d_in[8];
    const float* mb1  = (const float*)d_in[9];
    const float* mw2  = (const float*)d_in[10];
    const float* mb2  = (const float*)d_in[11];
    const float* few1 = (const float*)d_in[12];
    const float* few2 = (const float*)d_in[13];
    const float* feb2 = (const float*)d_in[14];
    const float* lng  = (const float*)d_in[15];
    const float* lnb  = (const float*)d_in[16];

    // workspace layout (floats), with dead-buffer reuse (2.62 MB total):
    float* ws    = (float*)d_ws;
    float* pool  = ws;            // [B,E]    163840   (dead after g1)
    float* t1    = ws + 163840;   // [B,2E]   327680   (dead after g2)
    float* cross = ws + 491520;   // [B,1280] 163840   (dead after g5)
    float* t2    = t1;            // [B,2E]   reuse t1
    float* t3    = pool;          // [B,1024] reuse pool
    float* pf    = cross;         // [B,H]    reuse cross

    float* out_x  = (float*)d_out;       // [B,E]
    float* out_px = out_x + 163840;      // [B,H]
    float* out_pf = out_x + 180224;      // [B,H]

    hipMemsetAsync(pool, 0, (size_t)B_ * E_ * sizeof(float), stream);
    pool_kernel<<<dim3(B_, NS_), 320, 0, stream>>>(esm, vlen, pool);
    standardize_kernel<<<FEAT_, B_, 0, stream>>>(ma, mb, cross);
    // x = relu(pool @ lw1 + lb1) @ lw2 + lb2
    gemm_kernel<<<dim3(2, 40), 256, 0, stream>>>(pool, lw1, lb1, t1, 128, 2560, 1280, 1);
    gemm_kernel<<<dim3(2, 20), 256, 0, stream>>>(t1, lw2, lb2, out_x, 128, 1280, 2560, 0);
    // proj_x = relu(x @ mw1 + mb1) @ mw2 + mb2
    gemm_kernel<<<dim3(2, 40), 256, 0, stream>>>(out_x, mw1, mb1, t2, 128, 2560, 1280, 1);
    gemm_kernel<<<dim3(2, 2), 256, 0, stream>>>(t2, mw2, mb2, out_px, 128, 128, 2560, 0);
    // proj_f = ln(relu(cross @ few1) @ few2 + feb2)
    gemm_kernel<<<dim3(2, 16), 256, 0, stream>>>(cross, few1, nullptr, t3, 128, 1024, 1280, 1);
    gemm_kernel<<<dim3(2, 2), 256, 0, stream>>>(t3, few2, feb2, pf, 128, 128, 1024, 0);
    ln_kernel<<<B_, H_, 0, stream>>>(pf, lng, lnb, out_pf);
}

// Round 2
// 1111.349 us; speedup vs baseline: 1.3748x; 1.3748x over previous
//
#include <hip/hip_runtime.h>
#include <math.h>

#define B_ 128
#define L_ 1024
#define E_ 1280
#define H_ 128
#define DA_ 512
#define DB_ 768
#define FEAT_ 1280
#define EPS_ 1e-5f
#define NS_ 16
#define CHUNK_ (L_ / NS_)   // 64 rows per slice

// ---------------- ragged mean pool ----------------
// grid (B, NS_), block 320 (E/4 float4 lanes). Each block sums rows
// [s*CHUNK, min((s+1)*CHUNK, len)) and atomically adds (sum/len) partials.
__global__ void pool_kernel(const float* __restrict__ esm,
                            const int* __restrict__ vlens,
                            float* __restrict__ pool) {
    const int b = blockIdx.x;
    const int s = blockIdx.y;
    const int len = vlens[b] + 2;
    int l0 = s * CHUNK_;
    int l1 = min(l0 + CHUNK_, len);
    if (l0 >= l1) return;
    const int e4 = threadIdx.x;  // 0..319
    const float4* base = (const float4*)esm + (size_t)b * L_ * (E_ / 4) + e4;
    float sx = 0.f, sy = 0.f, sz = 0.f, sw = 0.f;
    #pragma unroll 4
    for (int l = l0; l < l1; ++l) {
        float4 v = base[(size_t)l * (E_ / 4)];
        sx += v.x; sy += v.y; sz += v.z; sw += v.w;
    }
    const float inv = 1.0f / (float)len;
    float* dst = pool + (size_t)b * E_ + e4 * 4;
    atomicAdd(dst + 0, sx * inv);
    atomicAdd(dst + 1, sy * inv);
    atomicAdd(dst + 2, sz * inv);
    atomicAdd(dst + 3, sw * inv);
}

// ---------------- per-column standardize (over batch, ddof=1) ----------------
// Reference standardizes a/b then re-standardizes the concat; second pass is
// identity on already-standardized columns, so one pass suffices.
__global__ void standardize_kernel(const float* __restrict__ ma,
                                   const float* __restrict__ mb,
                                   float* __restrict__ cross) {
    const int c = blockIdx.x;   // 0..1279
    const int t = threadIdx.x;  // 0..127
    const float* src; int d, col;
    if (c < DA_) { src = ma; d = DA_; col = c; }
    else         { src = mb; d = DB_; col = c - DA_; }
    const float v = src[(size_t)t * d + col];
    __shared__ float red[B_];
    red[t] = v; __syncthreads();
    for (int off = B_ / 2; off > 0; off >>= 1) {
        if (t < off) red[t] += red[t + off];
        __syncthreads();
    }
    const float mean = red[0] * (1.0f / B_);
    __syncthreads();
    const float dv = v - mean;
    red[t] = dv * dv; __syncthreads();
    for (int off = B_ / 2; off > 0; off >>= 1) {
        if (t < off) red[t] += red[t + off];
        __syncthreads();
    }
    const float stdv = sqrtf(red[0] * (1.0f / (B_ - 1)));
    cross[(size_t)t * FEAT_ + c] = dv / stdv;
}

// ---------------- fp32 GEMM v2: double-buffered LDS + register prefetch ----
// C[(64x64 tile)] = act(A[M,K] @ W[K,N] + bias), optional split-K with
// fp32 atomicAdd epilogue (bias applied only by the kBegin==0 block).
// BM=BN=64, BK=16, 256 threads, 4x4 micro-tile.
// LDS leading dim 68: float4-aligned, worst 2-way bank aliasing (free).
__global__ __launch_bounds__(256) void gemm2_kernel(
    const float* __restrict__ A, const float* __restrict__ W,
    const float* __restrict__ bias, float* __restrict__ C,
    const int N, const int K, const int kChunk,
    const int relu, const int atomic) {
    __shared__ float As[2][16][68];  // [buf][k][m]
    __shared__ float Ws[2][16][68];  // [buf][k][n]
    const int bm = blockIdx.x * 64;
    const int bn = blockIdx.y * 64;
    const int kBegin = blockIdx.z * kChunk;
    const int kEnd = min(K, kBegin + kChunk);
    const int tid = threadIdx.x;
    const int tx = tid & 15;   // output col group
    const int ty = tid >> 4;   // output row group
    const int akk = tid & 15;  // A-load k
    const int ar  = tid >> 4;  // A-load row base
    const int wn  = tid & 63;  // W-load col
    const int wkb = tid >> 6;  // W-load k base
    const float* Abase = A + (size_t)(bm + ar) * K + akk;
    const float* Wbase = W + (size_t)wkb * N + bn + wn;

    float ra[4], rw[4];
    float acc[4][4] = {};

    // prologue: load first tile, stage to buf 0
    #pragma unroll
    for (int i = 0; i < 4; ++i) {
        ra[i] = Abase[(size_t)(i * 16) * K + kBegin];
        rw[i] = Wbase[(size_t)(kBegin + i * 4) * N];
    }
    #pragma unroll
    for (int i = 0; i < 4; ++i) {
        As[0][akk][ar + i * 16] = ra[i];
        Ws[0][wkb + i * 4][wn]  = rw[i];
    }
    __syncthreads();

    int buf = 0;
    for (int k0 = kBegin; k0 < kEnd; k0 += 16) {
        const int next = k0 + 16;
        const bool more = next < kEnd;
        if (more) {
            #pragma unroll
            for (int i = 0; i < 4; ++i) {
                ra[i] = Abase[(size_t)(i * 16) * K + next];
                rw[i] = Wbase[(size_t)(next + i * 4) * N];
            }
        }
        #pragma unroll
        for (int kk = 0; kk < 16; ++kk) {
            float4 a4 = *(const float4*)&As[buf][kk][ty * 4];
            float4 w4 = *(const float4*)&Ws[buf][kk][tx * 4];
            const float av[4] = {a4.x, a4.y, a4.z, a4.w};
            const float wv[4] = {w4.x, w4.y, w4.z, w4.w};
            #pragma unroll
            for (int i = 0; i < 4; ++i)
                #pragma unroll
                for (int j = 0; j < 4; ++j)
                    acc[i][j] += av[i] * wv[j];
        }
        if (more) {
            const int nb = buf ^ 1;
            #pragma unroll
            for (int i = 0; i < 4; ++i) {
                As[nb][akk][ar + i * 16] = ra[i];
                Ws[nb][wkb + i * 4][wn]  = rw[i];
            }
            __syncthreads();
            buf = nb;
        }
    }

    const bool addBias = (bias != nullptr) && (kBegin == 0);
    #pragma unroll
    for (int i = 0; i < 4; ++i) {
        const int row = bm + ty * 4 + i;
        float* crow = C + (size_t)row * N + bn + tx * 4;
        if (atomic) {
            #pragma unroll
            for (int j = 0; j < 4; ++j) {
                float v = acc[i][j];
                if (addBias) v += bias[bn + tx * 4 + j];
                atomicAdd(crow + j, v);
            }
        } else {
            float4 o;
            float* op = (float*)&o;
            #pragma unroll
            for (int j = 0; j < 4; ++j) {
                float v = acc[i][j];
                if (addBias) v += bias[bn + tx * 4 + j];
                if (relu) v = fmaxf(v, 0.0f);
                op[j] = v;
            }
            *(float4*)crow = o;
        }
    }
}

// ---------------- layernorm over last dim (H=128), ddof=0 ----------------
__global__ void ln_kernel(const float* __restrict__ x, const float* __restrict__ g,
                          const float* __restrict__ bt, float* __restrict__ out) {
    const int r = blockIdx.x;
    const int t = threadIdx.x;  // 0..127
    const float v = x[(size_t)r * H_ + t];
    __shared__ float red[H_];
    red[t] = v; __syncthreads();
    for (int off = H_ / 2; off > 0; off >>= 1) {
        if (t < off) red[t] += red[t + off];
        __syncthreads();
    }
    const float mean = red[0] * (1.0f / H_);
    __syncthreads();
    const float dv = v - mean;
    red[t] = dv * dv; __syncthreads();
    for (int off = H_ / 2; off > 0; off >>= 1) {
        if (t < off) red[t] += red[t + off];
        __syncthreads();
    }
    const float var = red[0] * (1.0f / H_);
    out[(size_t)r * H_ + t] = dv * rsqrtf(var + EPS_) * g[t] + bt[t];
}

extern "C" void kernel_launch(void* const* d_in, const int* in_sizes, int n_in,
                              void* d_out, int out_size, void* d_ws, size_t ws_size,
                              hipStream_t stream) {
    const float* esm  = (const float*)d_in[0];
    const int*   vlen = (const int*)d_in[1];
    const float* ma   = (const float*)d_in[2];
    const float* mb   = (const float*)d_in[3];
    const float* lw1  = (const float*)d_in[4];
    const float* lb1  = (const float*)d_in[5];
    const float* lw2  = (const float*)d_in[6];
    const float* lb2  = (const float*)d_in[7];
    const float* mw1  = (const float*)d_in[8];
    const float* mb1  = (const float*)d_in[9];
    const float* mw2  = (const float*)d_in[10];
    const float* mb2  = (const float*)d_in[11];
    const float* few1 = (const float*)d_in[12];
    const float* few2 = (const float*)d_in[13];
    const float* feb2 = (const float*)d_in[14];
    const float* lng  = (const float*)d_in[15];
    const float* lnb  = (const float*)d_in[16];

    // workspace layout (floats):
    float* ws     = (float*)d_ws;
    float* pool   = ws;            // [B,E]     163840  (zeroed: atomic pool)
    float* pf_acc = ws + 163840;   // [B,H]      16384  (zeroed: split-K g6)
    float* t1     = ws + 180224;   // [B,2E]    327680
    float* cross  = ws + 507904;   // [B,1280]  163840
    float* t2     = t1;            // reuse (t1 dead after g2)
    float* t3     = ws + 671744;   // [B,1024]  131072

    float* out_x  = (float*)d_out;       // [B,E]  (zeroed: split-K g2)
    float* out_px = out_x + 163840;      // [B,H]  (zeroed: split-K g4)
    float* out_pf = out_x + 180224;      // [B,H]

    hipMemsetAsync(ws, 0, (size_t)180224 * sizeof(float), stream);     // pool+pf_acc
    hipMemsetAsync(d_out, 0, (size_t)196608 * sizeof(float), stream);  // x, px (pf overwritten)

    pool_kernel<<<dim3(B_, NS_), 320, 0, stream>>>(esm, vlen, pool);
    standardize_kernel<<<FEAT_, B_, 0, stream>>>(ma, mb, cross);

    // x = relu(pool @ lw1 + lb1) @ lw2 + lb2
    gemm2_kernel<<<dim3(2, 40, 1), 256, 0, stream>>>(pool, lw1, lb1, t1, 2560, 1280, 1280, 1, 0);
    gemm2_kernel<<<dim3(2, 20, 2), 256, 0, stream>>>(t1, lw2, lb2, out_x, 1280, 2560, 1280, 0, 1);
    // proj_x = relu(x @ mw1 + mb1) @ mw2 + mb2
    gemm2_kernel<<<dim3(2, 40, 1), 256, 0, stream>>>(out_x, mw1, mb1, t2, 2560, 1280, 1280, 1, 0);
    gemm2_kernel<<<dim3(2, 2, 8), 256, 0, stream>>>(t2, mw2, mb2, out_px, 128, 2560, 320, 0, 1);
    // proj_f = ln(relu(cross @ few1) @ few2 + feb2)
    gemm2_kernel<<<dim3(2, 16, 1), 256, 0, stream>>>(cross, few1, nullptr, t3, 1024, 1280, 1280, 1, 0);
    gemm2_kernel<<<dim3(2, 2, 4), 256, 0, stream>>>(t3, few2, feb2, pf_acc, 128, 1024, 256, 0, 1);
    ln_kernel<<<B_, H_, 0, stream>>>(pf_acc, lng, lnb, out_pf);
}